// Round 13
// baseline (47.476 us; speedup 1.0000x reference)
//
#include <hip/hip_runtime.h>
#include <math.h>

#define W48 48
#define HD 2304
#define NR 32
#define QPP 27648            // float4 groups per (b,r) plane
#define CHUNKS 108           // QPP / 256
#define MAIN_BLOCKS 864      // 8 * CHUNKS
#define PARTS 432            // per-plane partials = CHUNKS * 4 waves
#define NPLANES 256
#define NTOT 28311552.0

struct PPart { float s0, sx, sy; unsigned key; unsigned idx; }; // 20 B

// ws layout (bytes)
#define PP_BYTES 2211840u              // 256*432*20
#define BLK_OFF  2211840u
#define PD_OFF   2246400u              // + 864*5*8
#define CNT_OFF  2248448u              // + 256*8

// ---- fused single-pass kernel: WAVE-PRIVATE epilogues, zero barriers in hot path ----
// Toolchain law (R6-R10): __launch_bounds__(256,N) caps VGPR at 256/N. N=2 -> 128 cap.
// R11 counters: latency-bound (VALU 20%, occ 21%, 0 conflicts). R12: depth-6 prefetch
// helped only 2.3us -> residual serialization is the 8-barrier convoy. This version
// makes the r16 reduce wave-private: no __syncthreads until the final div epilogue.
__global__ __launch_bounds__(256, 2)
void k_main(const float* __restrict__ feat, PPart* __restrict__ pp,
            double* __restrict__ blk) {
  __shared__ float    lds_s0[4][16 * 64];    // 16 KB: per-wave [r16][lane]
  __shared__ unsigned lds_key[4][16 * 64];   // 16 KB
  __shared__ unsigned lds_mc[4][64];         // 1 KB  packed mc, 2b per r16
  __shared__ double ld[4][5];

  const int bid = blockIdx.x;
  const int t = threadIdx.x;
  const int wave = t >> 6, lane = t & 63;
  const int b = bid / CHUNKS;
  const int chunk = bid - b * CHUNKS;
  const int qbase = chunk * 256 + t;
  const float4* gptr = reinterpret_cast<const float4*>(feat) + (size_t)b * (NR * QPP) + qbase;

  float* __restrict__ ws0 = lds_s0[wave];
  unsigned* __restrict__ wkey = lds_key[wave];
  unsigned* __restrict__ wmcA = lds_mc[wave];

  const int p0 = qbase * 4;
  const float fi = (float)(p0 / HD);
  const float fj = (float)((p0 / W48) % W48);   // constant over the 4 elems (4 | 48)
  const float rrq = fi * fi + fj * fj;

  float v1[4], v2[4], cp[4];
#pragma unroll
  for (int c = 0; c < 4; ++c) { v1[c] = -INFINITY; v2[c] = -INFINITY; cp[c] = 0.f; }
  float ssum = 0.f, sii = 0.f;
  unsigned mcpack = 0u;

  // 6-deep rotating prefetch (R12: +MLP proven)
  float4 nb0 = gptr[0];
  float4 nb1 = gptr[(size_t)QPP];
  float4 nb2 = gptr[2 * (size_t)QPP];
  float4 nb3 = gptr[3 * (size_t)QPP];
  float4 nb4 = gptr[4 * (size_t)QPP];
  float4 nb5 = gptr[5 * (size_t)QPP];

  for (int half = 0; half < 2; ++half) {
#pragma unroll 4
    for (int rr = 0; rr < 16; ++rr) {
      const int r = half * 16 + rr;
      float4 v = nb0;
      nb0 = nb1; nb1 = nb2; nb2 = nb3; nb3 = nb4; nb4 = nb5;
      int rn = r + 6; rn = (rn < NR) ? rn : (NR - 1);   // clamped redundant tail load
      nb5 = gptr[(size_t)rn * QPP];

      float vv[4] = {v.x, v.y, v.z, v.w};
      float f2[4];
#pragma unroll
      for (int c = 0; c < 4; ++c) {
        float f = vv[c];
        f2[c] = f * f;
        cp[c] += f2[c];
        ssum += f;
        float nv2 = fmaxf(f, v2[c]);
        v2[c] = (f > v1[c]) ? v1[c] : nv2;     // top-2 insert, first-index semantics
        v1[c] = fmaxf(v1[c], f);
      }
      float s0t = (f2[0] + f2[1]) + (f2[2] + f2[3]);
      sii += s0t * rrq;

      float mv = vv[0]; int mc = 0;
#pragma unroll
      for (int c = 1; c < 4; ++c) { if (vv[c] > mv) { mv = vv[c]; mc = c; } }  // strict >
      unsigned u = __float_as_uint(mv);
      unsigned key = u ^ ((unsigned)((int)u >> 31) | 0x80000000u);  // order-preserving

      mcpack |= (unsigned)mc << (2 * rr);
      ws0[rr * 64 + lane] = s0t;
      wkey[rr * 64 + lane] = key;
    }

    // ---- WAVE-PRIVATE epilogue: no block barrier. Lockstep wave64 + lgkmcnt
    // ordering make LDS write->read safe; wave_barrier pins scheduling. ----
    wmcA[lane] = mcpack; mcpack = 0u;
    __asm__ __volatile__("" ::: "memory");
    __builtin_amdgcn_wave_barrier();

    const int er = lane & 15;                // which r this lane reduces
    const int eg = lane >> 4;                // which 16-lane row group
    float es0 = 0.f, esx = 0.f, esy = 0.f;
    unsigned bk = 0u; int brow = 0;          // real keys are always > 0
#pragma unroll
    for (int k = 0; k < 16; ++k) {
      int row = eg * 16 + ((k + er) & 15);   // rotation: 2-way bank alias only (free)
      float s0v   = ws0[er * 64 + row];
      unsigned kv = wkey[er * 64 + row];
      unsigned g = (unsigned)(chunk * 256 + wave * 64 + row);
      float fiq = (float)(g / 576u);         // i = 4g/2304
      float fjq = (float)((g / 12u) % 48u);  // j = (4g/48)%48
      es0 += s0v;
      esx = fmaf(s0v, fiq, esx);
      esy = fmaf(s0v, fjq, esy);
      if (kv > bk || (kv == bk && row < brow)) { bk = kv; brow = row; }
    }
    unsigned wmc = (wmcA[brow] >> (2 * er)) & 3u;
    unsigned bidx = (unsigned)((chunk * 256 + wave * 64 + brow) * 4) + wmc;

    // combine the 4 eg-partials per er across lane bits 4,5
#pragma unroll
    for (int m = 16; m <= 32; m <<= 1) {
      es0 += __shfl_xor(es0, m);
      esx += __shfl_xor(esx, m);
      esy += __shfl_xor(esy, m);
      unsigned ok = (unsigned)__shfl_xor((int)bk, m);
      unsigned oi = (unsigned)__shfl_xor((int)bidx, m);
      if (ok > bk || (ok == bk && oi < bidx)) { bk = ok; bidx = oi; }
    }
    if (lane < 16) {
      int plane = b * NR + half * 16 + lane;
      PPart o; o.s0 = es0; o.sx = esx; o.sy = esy; o.key = bk; o.idx = bidx;
      pp[(size_t)plane * PARTS + chunk * 4 + wave] = o;
    }
    __builtin_amdgcn_wave_barrier();         // arena reuse for next half (wave-local)
    __asm__ __volatile__("" ::: "memory");
  }

  // ---- div epilogue (f2@argmax == v1^2) + global sums: one block barrier total ----
  float A = 0.f, Bs = 0.f, C = 0.f;
#pragma unroll
  for (int c = 0; c < 4; ++c) {
    float m1 = v1[c], m1sq = m1 * m1;
    float rest = cp[c] - m1sq;
    A  += m1sq * rest + v2[c] * v2[c] * m1sq;
    Bs += m1 * rest + v2[c] * m1sq;
    C  += cp[c];
  }
  double dA = A, dB = Bs, dC = C, dS = ssum, dI = sii;
#pragma unroll
  for (int off = 32; off; off >>= 1) {
    dA += __shfl_down(dA, off);
    dB += __shfl_down(dB, off);
    dC += __shfl_down(dC, off);
    dS += __shfl_down(dS, off);
    dI += __shfl_down(dI, off);
  }
  if (lane == 0) { ld[wave][0]=dA; ld[wave][1]=dB; ld[wave][2]=dC; ld[wave][3]=dS; ld[wave][4]=dI; }
  __syncthreads();
  if (t == 0) {
    double a=0, bb=0, cc=0, ss=0, si=0;
#pragma unroll
    for (int w = 0; w < 4; ++w) { a+=ld[w][0]; bb+=ld[w][1]; cc+=ld[w][2]; ss+=ld[w][3]; si+=ld[w][4]; }
    blk[(size_t)bid*5+0]=a; blk[(size_t)bid*5+1]=bb; blk[(size_t)bid*5+2]=cc;
    blk[(size_t)bid*5+3]=ss; blk[(size_t)bid*5+4]=si;
  }
}

// ---- fused tail: per-plane combine (coalesced pp reads) + last-block finalize ----
__global__ __launch_bounds__(128)
void k_tail(const PPart* __restrict__ pp, const double* __restrict__ blk,
            double* __restrict__ planeDis, unsigned* __restrict__ counter,
            float* __restrict__ out) {
  __shared__ double ls[2][3];
  __shared__ unsigned lk[2][2];
  __shared__ double fin[2][6];
  __shared__ int lastFlag;

  const int p = blockIdx.x;               // one block per plane
  const int t = threadIdx.x;
  const int wave = t >> 6, lane = t & 63;

  // part 1: combine 432 wave-partials of plane p (contiguous -> coalesced)
  double s0 = 0, sx = 0, sy = 0;
  unsigned key = 0, idx = 0xffffffffu;
#pragma unroll
  for (int k = 0; k < 4; ++k) {
    int i = t + 128 * k;
    if (i < PARTS) {
      PPart v = pp[(size_t)p * PARTS + i];
      s0 += v.s0; sx += v.sx; sy += v.sy;
      if (v.key > key || (v.key == key && v.idx < idx)) { key = v.key; idx = v.idx; }
    }
  }
#pragma unroll
  for (int off = 32; off; off >>= 1) {
    s0 += __shfl_down(s0, off);
    sx += __shfl_down(sx, off);
    sy += __shfl_down(sy, off);
    unsigned ok = (unsigned)__shfl_down((int)key, off);
    unsigned oi = (unsigned)__shfl_down((int)idx, off);
    if (ok > key || (ok == key && oi < idx)) { key = ok; idx = oi; }
  }
  if (lane == 0) { ls[wave][0]=s0; ls[wave][1]=sx; ls[wave][2]=sy; lk[wave][0]=key; lk[wave][1]=idx; }
  __syncthreads();
  if (t == 0) {
    double a0 = ls[0][0] + ls[1][0], a1 = ls[0][1] + ls[1][1], a2 = ls[0][2] + ls[1][2];
    unsigned bk = lk[0][0], bi = lk[0][1];
    if (lk[1][0] > bk || (lk[1][0] == bk && lk[1][1] < bi)) { bk = lk[1][0]; bi = lk[1][1]; }
    int am = (int)bi;
    int mx = am / HD;
    int rem = am - mx * HD;
    int my = rem / W48;
    int mz = rem - my * W48;
    double dmx = mx, dmy = my, dmz = mz;
    // sum_k (mz-k)^2, k=0..47 = 48 mz^2 - 2256 mz + 35720 ; times W*H=2304
    planeDis[p] = (dmx*dmx + dmy*dmy) * a0 - 2.0*dmx*a1 - 2.0*dmy*a2
                + 2304.0 * (48.0*dmz*dmz - 2256.0*dmz + 35720.0);
    __threadfence();                            // release planeDis[p]
    lastFlag = (atomicAdd(counter, 1u) == NPLANES - 1u);
  }
  __syncthreads();

  if (lastFlag) {
    __threadfence();                            // acquire peers' planeDis
    double dis = planeDis[t] + planeDis[t + 128];
    double A = 0, B = 0, C = 0, S = 0, SI = 0;
#pragma unroll
    for (int k = 0; k < 7; ++k) {
      int i = t + 128 * k;
      if (i < MAIN_BLOCKS) {
        const double* bb = blk + (size_t)i * 5;
        A += bb[0]; B += bb[1]; C += bb[2]; S += bb[3]; SI += bb[4];
      }
    }
#pragma unroll
    for (int off = 32; off; off >>= 1) {
      dis += __shfl_down(dis, off);
      A   += __shfl_down(A, off);
      B   += __shfl_down(B, off);
      C   += __shfl_down(C, off);
      S   += __shfl_down(S, off);
      SI  += __shfl_down(SI, off);
    }
    if (lane == 0) {
      fin[wave][0]=dis; fin[wave][1]=A; fin[wave][2]=B;
      fin[wave][3]=C;   fin[wave][4]=S; fin[wave][5]=SI;
    }
    __syncthreads();
    if (t == 0) {
      double td = fin[0][0]+fin[1][0], tA = fin[0][1]+fin[1][1], tB = fin[0][2]+fin[1][2];
      double tC = fin[0][3]+fin[1][3], tS = fin[0][4]+fin[1][4], tI = fin[0][5]+fin[1][5];
      double mgr = tS / NTOT;
      out[0] = (float)((td + tI) / NTOT);
      out[1] = (float)((tA - 2.0*mgr*tB + mgr*mgr*tC) / NTOT);
    }
  }
}

extern "C" void kernel_launch(void* const* d_in, const int* in_sizes, int n_in,
                              void* d_out, int out_size, void* d_ws, size_t ws_size,
                              hipStream_t stream) {
  // inputs: [0]=backbone_feature (unused), [1]=grouping_result (unused), [2]=feature
  const float* feat = (const float*)d_in[2];
  float* out = (float*)d_out;

  PPart* pp        = (PPart*)d_ws;
  double* blk      = (double*)((char*)d_ws + BLK_OFF);
  double* planeDis = (double*)((char*)d_ws + PD_OFF);
  unsigned* cnt    = (unsigned*)((char*)d_ws + CNT_OFF);

  hipMemsetAsync(cnt, 0, 4, stream);            // reset last-block counter each launch
  k_main<<<MAIN_BLOCKS, 256, 0, stream>>>(feat, pp, blk);
  k_tail<<<NPLANES, 128, 0, stream>>>(pp, blk, planeDis, cnt, out);
}